// Round 6
// baseline (480.240 us; speedup 1.0000x reference)
//
#include <hip/hip_runtime.h>
#include <hip/hip_bf16.h>
#include <math.h>

// Problem dims (fixed by reference)
#define BB 64
#define SS 200
#define TT 32
#define EE 128
#define CC 128
#define HH 100
#define G3 300           // 3*H
#define OUTD 104
#define NTREE (BB*SS)    // 12800

typedef __attribute__((ext_vector_type(8))) short short8;
typedef __attribute__((ext_vector_type(4))) float f32x4;
typedef _Float16 f16x8 __attribute__((ext_vector_type(8)));

__device__ inline unsigned short f2bf_rne(float f) {
    union { float f; unsigned u; } x; x.f = f;
    unsigned r = (x.u + 0x7FFFu + ((x.u >> 16) & 1u)) >> 16;
    return (unsigned short)r;
}
__device__ inline float bf2f(unsigned short h) {
    union { unsigned u; float f; } x; x.u = ((unsigned)h) << 16;
    return x.f;
}
__device__ inline float fast_sigmoid(float x) {
    return __builtin_amdgcn_rcpf(1.f + __builtin_amdgcn_exp2f(-1.4426950408889634f * x));
}
__device__ inline float fast_tanh(float x) {
    return 1.f - 2.f * __builtin_amdgcn_rcpf(1.f + __builtin_amdgcn_exp2f(2.8853900817779268f * x));
}

// LDS-only barrier: waits ds-ops (lgkmcnt) but does NOT drain vmcnt, so in-flight
// global prefetch loads stay outstanding across the barrier (waited at use).
#define BAR() asm volatile("s_waitcnt lgkmcnt(0)\n\ts_barrier" ::: "memory")

// ---------------- K1 (MFMA): embed-gather -> bf16 GEMM vs W_lin^T -> bias -> tree-sum -> maxpool
#define K1_TPI 2
#define AROWS (K1_TPI*TT)        // 64
#define LDA 136                  // bf16/row: 128 + 8 pad
#define LDC 132                  // fp32/row: 128 + 4 pad

__global__ __launch_bounds__(256) void k1_mfma(const int* __restrict__ tok,
                                               const float* __restrict__ emb,
                                               const float* __restrict__ w_lin,
                                               const float* __restrict__ b_lin,
                                               float* __restrict__ tree_vec) {
    __shared__ __align__(16) unsigned short A_sh[AROWS * LDA];   // 17408 B
    __shared__ __align__(16) float C_sh[AROWS * LDC];            // 33792 B
    __shared__ int tok_sh[AROWS];

    const int tid  = threadIdx.x;
    const int wave = tid >> 6;
    const int lane = tid & 63;
    const int r = lane & 15;
    const int q = lane >> 4;

    short8 bfrag[2][4];
    float  bias[2];
#pragma unroll
    for (int nt = 0; nt < 2; ++nt) {
        const int n = wave * 32 + nt * 16 + r;
        bias[nt] = b_lin[n];
#pragma unroll
        for (int kt = 0; kt < 4; ++kt) {
            const float* src = w_lin + (long)n * EE + kt * 32 + q * 8;
            float4 a = ((const float4*)src)[0];
            float4 b = ((const float4*)src)[1];
            short8 f;
            f[0] = (short)f2bf_rne(a.x); f[1] = (short)f2bf_rne(a.y);
            f[2] = (short)f2bf_rne(a.z); f[3] = (short)f2bf_rne(a.w);
            f[4] = (short)f2bf_rne(b.x); f[5] = (short)f2bf_rne(b.y);
            f[6] = (short)f2bf_rne(b.z); f[7] = (short)f2bf_rne(b.w);
            bfrag[nt][kt] = f;
        }
    }

    const int tree0 = blockIdx.x * K1_TPI;
    if (tid < AROWS) tok_sh[tid] = tok[tree0 * TT + tid];
    __syncthreads();

#pragma unroll
    for (int i = 0; i < 8; ++i) {
        const int idx = tid + i * 256;
        const int row = idx >> 5;
        const int p   = idx & 31;
        const float4 e = ((const float4*)(emb + (long)tok_sh[row] * EE))[p];
        unsigned short* dst = &A_sh[row * LDA + p * 4];
        dst[0] = f2bf_rne(e.x); dst[1] = f2bf_rne(e.y);
        dst[2] = f2bf_rne(e.z); dst[3] = f2bf_rne(e.w);
    }
    __syncthreads();

    f32x4 acc[4][2];
#pragma unroll
    for (int mt = 0; mt < 4; ++mt)
#pragma unroll
        for (int nt = 0; nt < 2; ++nt) acc[mt][nt] = (f32x4)(0.f);

#pragma unroll
    for (int mt = 0; mt < 4; ++mt) {
        const int m = mt * 16 + r;
        short8 afrag[4];
#pragma unroll
        for (int kt = 0; kt < 4; ++kt)
            afrag[kt] = *(const short8*)&A_sh[m * LDA + kt * 32 + q * 8];
#pragma unroll
        for (int nt = 0; nt < 2; ++nt)
#pragma unroll
            for (int kt = 0; kt < 4; ++kt)
                acc[mt][nt] = __builtin_amdgcn_mfma_f32_16x16x32_bf16(
                    afrag[kt], bfrag[nt][kt], acc[mt][nt], 0, 0, 0);
    }

#pragma unroll
    for (int mt = 0; mt < 4; ++mt)
#pragma unroll
        for (int nt = 0; nt < 2; ++nt) {
            const int col = wave * 32 + nt * 16 + r;
#pragma unroll
            for (int reg = 0; reg < 4; ++reg) {
                const int row = mt * 16 + q * 4 + reg;
                C_sh[row * LDC + col] = acc[mt][nt][reg] + bias[nt];
            }
        }
    __syncthreads();

    {
        const int t = tid >> 7;
        const int j = tid & 127;
        const float* base = &C_sh[(t * TT) * LDC + j];
        float v[TT];
#pragma unroll
        for (int n = 0; n < TT; ++n) v[n] = base[n * LDC];
        float m = -1e30f;
#pragma unroll
        for (int n = TT - 1; n >= 1; --n) {
            m = fmaxf(m, v[n]);
            v[(n - 1) >> 1] += v[n];
        }
        m = fmaxf(m, v[0]);
        tree_vec[(long)(tree0 + t) * CC + j] = m;
    }
}

// ---------------- K2 (MFMA, hi/lo split): gx[dir][m=b*S+s][300] = X @ W_ih^T + b_ih
#define K2_NPAD 320
__global__ __launch_bounds__(256) void k2_mfma(const float* __restrict__ tree_vec,
                                               const float* __restrict__ w_ih_f,
                                               const float* __restrict__ b_ih_f,
                                               const float* __restrict__ w_ih_b,
                                               const float* __restrict__ b_ih_b,
                                               float* __restrict__ gx) {
    __shared__ __align__(16) unsigned short Ahi[32 * LDA];
    __shared__ __align__(16) unsigned short Alo[32 * LDA];
    __shared__ __align__(16) unsigned short Bhi[64 * LDA];
    __shared__ __align__(16) unsigned short Blo[64 * LDA];

    const int tid  = threadIdx.x;
    const int wave = tid >> 6;
    const int lane = tid & 63;
    const int r = lane & 15;
    const int q = lane >> 4;

    const int nb = blockIdx.x % 10;
    const int mb = blockIdx.x / 10;
    const int m0 = mb * 32;
    const int n0 = nb * 64;

#pragma unroll
    for (int i = 0; i < 4; ++i) {
        const int idx = tid + i * 256;
        const int row = idx >> 5;
        const int p   = idx & 31;
        const float4 v = ((const float4*)(tree_vec + (long)(m0 + row) * CC))[p];
        unsigned short* dh = &Ahi[row * LDA + p * 4];
        unsigned short* dl = &Alo[row * LDA + p * 4];
        float e[4] = {v.x, v.y, v.z, v.w};
#pragma unroll
        for (int c = 0; c < 4; ++c) {
            unsigned short h = f2bf_rne(e[c]);
            dh[c] = h;
            dl[c] = f2bf_rne(e[c] - bf2f(h));
        }
    }
#pragma unroll
    for (int i = 0; i < 8; ++i) {
        const int idx = tid + i * 256;
        const int row = idx >> 5;
        const int p   = idx & 31;
        const int n   = n0 + row;
        const int dir = (n >= K2_NPAD) ? 1 : 0;
        const int j   = n - dir * K2_NPAD;
        const int jj  = (j < G3) ? j : 0;
        const float* w = dir ? w_ih_b : w_ih_f;
        const float4 v = ((const float4*)(w + (long)jj * EE))[p];
        unsigned short* dh = &Bhi[row * LDA + p * 4];
        unsigned short* dl = &Blo[row * LDA + p * 4];
        float e[4] = {v.x, v.y, v.z, v.w};
#pragma unroll
        for (int c = 0; c < 4; ++c) {
            unsigned short h = f2bf_rne(e[c]);
            dh[c] = h;
            dl[c] = f2bf_rne(e[c] - bf2f(h));
        }
    }
    __syncthreads();

    const int nloc = wave * 16 + r;
    short8 bh[4], bl[4];
#pragma unroll
    for (int kt = 0; kt < 4; ++kt) {
        bh[kt] = *(const short8*)&Bhi[nloc * LDA + kt * 32 + q * 8];
        bl[kt] = *(const short8*)&Blo[nloc * LDA + kt * 32 + q * 8];
    }

    f32x4 acc[2];
    acc[0] = (f32x4)(0.f); acc[1] = (f32x4)(0.f);
#pragma unroll
    for (int mt = 0; mt < 2; ++mt) {
        const int m = mt * 16 + r;
#pragma unroll
        for (int kt = 0; kt < 4; ++kt) {
            short8 ah = *(const short8*)&Ahi[m * LDA + kt * 32 + q * 8];
            short8 al = *(const short8*)&Alo[m * LDA + kt * 32 + q * 8];
            acc[mt] = __builtin_amdgcn_mfma_f32_16x16x32_bf16(ah, bh[kt], acc[mt], 0, 0, 0);
            acc[mt] = __builtin_amdgcn_mfma_f32_16x16x32_bf16(ah, bl[kt], acc[mt], 0, 0, 0);
            acc[mt] = __builtin_amdgcn_mfma_f32_16x16x32_bf16(al, bh[kt], acc[mt], 0, 0, 0);
        }
    }

    const int ng  = n0 + wave * 16 + r;
    const int dir = (ng >= K2_NPAD) ? 1 : 0;
    const int j   = ng - dir * K2_NPAD;
    const bool valid = (j < G3);
    const float bias = valid ? (dir ? b_ih_b[j] : b_ih_f[j]) : 0.f;
    float* gxd = gx + (long)dir * NTREE * G3;
    if (valid) {
#pragma unroll
        for (int mt = 0; mt < 2; ++mt)
#pragma unroll
            for (int reg = 0; reg < 4; ++reg) {
                const int m = m0 + mt * 16 + q * 4 + reg;
                gxd[(long)m * G3 + j] = acc[mt][reg] + bias;
            }
    }
}

// ---------------- K3 v4: 16 chains/block (8 blocks), fp16 single-term MFMA matvec,
// lgkm-only barriers. C[16 chains][300 gates] = H[16x100] . W_hh^T per step.
#define K3_CH 16
#define K3_LH 136                 // fp16 h row stride (16B-aligned, zero-padded k>=100)
#define K3_LG 306                 // gates row stride in floats (2-way max on C-writes)
__global__ __launch_bounds__(256, 1) void k3_gru(const float* __restrict__ gx,
                                                 const float* __restrict__ w_hh_f,
                                                 const float* __restrict__ b_hh_f,
                                                 const float* __restrict__ w_hh_b,
                                                 const float* __restrict__ b_hh_b,
                                                 float* __restrict__ pool) {
    const int bid = blockIdx.x;          // 0..7
    const int dir = bid >> 2;            // blocks 0-3 fwd, 4-7 bwd
    const int b0  = (bid & 3) * K3_CH;   // first batch row of this block
    const float* w_hh = dir ? w_hh_b : w_hh_f;
    const float* b_hh = dir ? b_hh_b : b_hh_f;

    __shared__ __align__(16) _Float16 h_sh[K3_CH * K3_LH];   // 4352 B
    __shared__ float gates_sh[K3_CH * K3_LG];                // 19584 B

    const int tid  = threadIdx.x;
    const int wave = tid >> 6;
    const int lane = tid & 63;
    const int r = lane & 15;
    const int q = lane >> 4;

    // ---- persistent B fragments (fp16): B[k][n] = W_hh[n][k]; lane(r,q) holds
    // n = ntg*16+r, k = kt*32 + q*8 + e. 19 n-tiles over 4 waves (wave w: 5, last 4).
    f16x8 bf[5][4];
    float bias[5];
#pragma unroll
    for (int i = 0; i < 5; ++i) {
        const int ntg = wave * 5 + i;
        const int n = ntg * 16 + r;
        const bool nv = (ntg < 19) && (n < G3);
        bias[i] = nv ? b_hh[n] : 0.f;
#pragma unroll
        for (int kt = 0; kt < 4; ++kt) {
            f16x8 f;
#pragma unroll
            for (int e = 0; e < 8; ++e) {
                const int k = kt * 32 + q * 8 + e;
                const float v = (nv && k < HH) ? w_hh[n * HH + k] : 0.f;
                f[e] = (_Float16)v;
            }
            bf[i][kt] = f;
        }
    }

    // zero h (incl. k-pad)
    for (int i = tid; i < K3_CH * K3_LH; i += 256) h_sh[i] = (_Float16)0.f;

    const float* gxd = gx + (long)dir * NTREE * G3;
    const int sstep = dir ? -1 : 1;
    int s = dir ? (SS - 1) : 0;

    // phase-2 ownership: thread t owns chain = t>>4, channels j = (t&15) + 16*i
    const int chain = tid >> 4;
    const int l16   = tid & 15;
    const long browbase = (long)(b0 + chain) * SS;

    float xr[7], xz[7], xn[7], hj[7], hmax[7];
#pragma unroll
    for (int i = 0; i < 7; ++i) { xr[i] = xz[i] = xn[i] = 0.f; hj[i] = 0.f; hmax[i] = -1e30f; }
    {
        const float* row = gxd + (browbase + s) * G3;
#pragma unroll
        for (int i = 0; i < 7; ++i) {
            const int j = l16 + 16 * i;
            if (j < HH) { xr[i] = row[j]; xz[i] = row[HH + j]; xn[i] = row[2 * HH + j]; }
        }
    }
    __syncthreads();

    for (int t = 0; t < SS; ++t) {
        // ---- prefetch next step's gx (not drained at barriers; waited at use)
        const int s_n = s + sstep;
        float xrn[7], xzn[7], xnn[7];
#pragma unroll
        for (int i = 0; i < 7; ++i) { xrn[i] = xzn[i] = xnn[i] = 0.f; }
        if (t < SS - 1) {
            const float* row = gxd + (browbase + s_n) * G3;
#pragma unroll
            for (int i = 0; i < 7; ++i) {
                const int j = l16 + 16 * i;
                if (j < HH) { xrn[i] = row[j]; xzn[i] = row[HH + j]; xnn[i] = row[2 * HH + j]; }
            }
        }

        // ---- phase 1: C[chain][n] = sum_k H[chain][k] * W_hh[n][k]
        f16x8 a[4];
#pragma unroll
        for (int kt = 0; kt < 4; ++kt)
            a[kt] = *(const f16x8*)&h_sh[r * K3_LH + kt * 32 + q * 8];
#pragma unroll
        for (int i = 0; i < 5; ++i) {
            const int ntg = wave * 5 + i;
            if (ntg < 19) {
                f32x4 acc = (f32x4)(0.f);
#pragma unroll
                for (int kt = 0; kt < 4; ++kt)
                    acc = __builtin_amdgcn_mfma_f32_16x16x32_f16(a[kt], bf[i][kt], acc, 0, 0, 0);
                const int n = ntg * 16 + r;
                if (n < G3) {
#pragma unroll
                    for (int reg = 0; reg < 4; ++reg)
                        gates_sh[(q * 4 + reg) * K3_LG + n] = acc[reg] + bias[i];
                }
            }
        }
        BAR();

        // ---- phase 2: h update for owned (chain, j) pairs
#pragma unroll
        for (int i = 0; i < 7; ++i) {
            const int j = l16 + 16 * i;
            if (j < HH) {
                const float ghr = gates_sh[chain * K3_LG + j];
                const float ghz = gates_sh[chain * K3_LG + HH + j];
                const float ghn = gates_sh[chain * K3_LG + 2 * HH + j];
                const float rg = fast_sigmoid(xr[i] + ghr);
                const float zg = fast_sigmoid(xz[i] + ghz);
                const float ng = fast_tanh(xn[i] + rg * ghn);
                hj[i] = (1.f - zg) * ng + zg * hj[i];
                hmax[i] = fmaxf(hmax[i], hj[i]);
                h_sh[chain * K3_LH + j] = (_Float16)hj[i];
            }
            xr[i] = xrn[i]; xz[i] = xzn[i]; xn[i] = xnn[i];
        }
        BAR();
        s = s_n;
    }

#pragma unroll
    for (int i = 0; i < 7; ++i) {
        const int j = l16 + 16 * i;
        if (j < HH) pool[(long)(b0 + chain) * (2 * HH) + dir * HH + j] = hmax[i];
    }
}

// ---------------- K4: out[b][o] = fc_b[o] + pool[b,:] . fc_w[o,:]
__global__ __launch_bounds__(256) void k4_fc(const float* __restrict__ pool,
                                             const float* __restrict__ fc_w,
                                             const float* __restrict__ fc_b,
                                             float* __restrict__ out) {
    const int b = blockIdx.x;
    __shared__ __align__(16) float p_sh[2 * HH];
    const int t = threadIdx.x;
    if (t < 2 * HH) p_sh[t] = pool[(long)b * (2 * HH) + t];
    __syncthreads();
    if (t < OUTD) {
        const float4* wr4 = (const float4*)(fc_w + (long)t * (2 * HH));
        const float4* p4 = (const float4*)p_sh;
        float a0 = 0.f, a1 = 0.f;
#pragma unroll
        for (int k = 0; k < 50; k += 2) {
            float4 w0 = wr4[k],   p0 = p4[k];
            float4 w1 = wr4[k+1], p1 = p4[k+1];
            a0 += w0.x*p0.x + w0.y*p0.y + w0.z*p0.z + w0.w*p0.w;
            a1 += w1.x*p1.x + w1.y*p1.y + w1.z*p1.z + w1.w*p1.w;
        }
        out[(long)b * OUTD + t] = fc_b[t] + a0 + a1;
    }
}

extern "C" void kernel_launch(void* const* d_in, const int* in_sizes, int n_in,
                              void* d_out, int out_size, void* d_ws, size_t ws_size,
                              hipStream_t stream) {
    const int*   tok    = (const int*)d_in[0];
    const float* emb    = (const float*)d_in[4];
    const float* w_lin  = (const float*)d_in[5];
    const float* b_lin  = (const float*)d_in[6];
    const float* w_ih_f = (const float*)d_in[7];
    const float* w_hh_f = (const float*)d_in[8];
    const float* b_ih_f = (const float*)d_in[9];
    const float* b_hh_f = (const float*)d_in[10];
    const float* w_ih_b = (const float*)d_in[11];
    const float* w_hh_b = (const float*)d_in[12];
    const float* b_ih_b = (const float*)d_in[13];
    const float* b_hh_b = (const float*)d_in[14];
    const float* fc_w   = (const float*)d_in[15];
    const float* fc_b   = (const float*)d_in[16];

    float* ws       = (float*)d_ws;
    float* tree_vec = ws;                                   // 12800*128
    float* gx       = tree_vec + (long)NTREE * CC;          // 2*12800*300
    float* pool     = gx + (long)2 * NTREE * G3;            // 64*200
    float* out      = (float*)d_out;

    k1_mfma<<<NTREE / K1_TPI, 256, 0, stream>>>(tok, emb, w_lin, b_lin, tree_vec);
    k2_mfma<<<(NTREE / 32) * 10, 256, 0, stream>>>(tree_vec, w_ih_f, b_ih_f, w_ih_b, b_ih_b, gx);
    k3_gru <<<8, 256, 0, stream>>>(gx, w_hh_f, b_hh_f, w_hh_b, b_hh_b, pool);
    k4_fc  <<<BB, 256, 0, stream>>>(pool, fc_w, fc_b, out);
}

// Round 7
// 276.464 us; speedup vs baseline: 1.7371x; 1.7371x over previous
//
#include <hip/hip_runtime.h>
#include <hip/hip_bf16.h>
#include <math.h>

// Problem dims (fixed by reference)
#define BB 64
#define SS 200
#define TT 32
#define EE 128
#define CC 128
#define HH 100
#define G3 300           // 3*H
#define OUTD 104
#define NTREE (BB*SS)    // 12800

typedef __attribute__((ext_vector_type(8))) short short8;
typedef __attribute__((ext_vector_type(4))) float f32x4;
typedef _Float16 f16x8 __attribute__((ext_vector_type(8)));

__device__ inline unsigned short f2bf_rne(float f) {
    union { float f; unsigned u; } x; x.f = f;
    unsigned r = (x.u + 0x7FFFu + ((x.u >> 16) & 1u)) >> 16;
    return (unsigned short)r;
}
__device__ inline float bf2f(unsigned short h) {
    union { unsigned u; float f; } x; x.u = ((unsigned)h) << 16;
    return x.f;
}
__device__ inline float fast_sigmoid(float x) {
    return __builtin_amdgcn_rcpf(1.f + __builtin_amdgcn_exp2f(-1.4426950408889634f * x));
}
__device__ inline float fast_tanh(float x) {
    return 1.f - 2.f * __builtin_amdgcn_rcpf(1.f + __builtin_amdgcn_exp2f(2.8853900817779268f * x));
}

// LDS-only barrier: waits ds-ops (lgkmcnt) but does NOT drain vmcnt, so in-flight
// global prefetch loads stay outstanding across the barrier (waited at use).
#define BAR() asm volatile("s_waitcnt lgkmcnt(0)\n\ts_barrier" ::: "memory")

// ---------------- K1 (MFMA): embed-gather -> bf16 GEMM vs W_lin^T -> bias -> tree-sum -> maxpool
#define K1_TPI 2
#define AROWS (K1_TPI*TT)        // 64
#define LDA 136                  // bf16/row: 128 + 8 pad
#define LDC 132                  // fp32/row: 128 + 4 pad

__global__ __launch_bounds__(256) void k1_mfma(const int* __restrict__ tok,
                                               const float* __restrict__ emb,
                                               const float* __restrict__ w_lin,
                                               const float* __restrict__ b_lin,
                                               float* __restrict__ tree_vec) {
    __shared__ __align__(16) unsigned short A_sh[AROWS * LDA];   // 17408 B
    __shared__ __align__(16) float C_sh[AROWS * LDC];            // 33792 B
    __shared__ int tok_sh[AROWS];

    const int tid  = threadIdx.x;
    const int wave = tid >> 6;
    const int lane = tid & 63;
    const int r = lane & 15;
    const int q = lane >> 4;

    short8 bfrag[2][4];
    float  bias[2];
#pragma unroll
    for (int nt = 0; nt < 2; ++nt) {
        const int n = wave * 32 + nt * 16 + r;
        bias[nt] = b_lin[n];
#pragma unroll
        for (int kt = 0; kt < 4; ++kt) {
            const float* src = w_lin + (long)n * EE + kt * 32 + q * 8;
            float4 a = ((const float4*)src)[0];
            float4 b = ((const float4*)src)[1];
            short8 f;
            f[0] = (short)f2bf_rne(a.x); f[1] = (short)f2bf_rne(a.y);
            f[2] = (short)f2bf_rne(a.z); f[3] = (short)f2bf_rne(a.w);
            f[4] = (short)f2bf_rne(b.x); f[5] = (short)f2bf_rne(b.y);
            f[6] = (short)f2bf_rne(b.z); f[7] = (short)f2bf_rne(b.w);
            bfrag[nt][kt] = f;
        }
    }

    const int tree0 = blockIdx.x * K1_TPI;
    if (tid < AROWS) tok_sh[tid] = tok[tree0 * TT + tid];
    __syncthreads();

#pragma unroll
    for (int i = 0; i < 8; ++i) {
        const int idx = tid + i * 256;
        const int row = idx >> 5;
        const int p   = idx & 31;
        const float4 e = ((const float4*)(emb + (long)tok_sh[row] * EE))[p];
        unsigned short* dst = &A_sh[row * LDA + p * 4];
        dst[0] = f2bf_rne(e.x); dst[1] = f2bf_rne(e.y);
        dst[2] = f2bf_rne(e.z); dst[3] = f2bf_rne(e.w);
    }
    __syncthreads();

    f32x4 acc[4][2];
#pragma unroll
    for (int mt = 0; mt < 4; ++mt)
#pragma unroll
        for (int nt = 0; nt < 2; ++nt) acc[mt][nt] = (f32x4)(0.f);

#pragma unroll
    for (int mt = 0; mt < 4; ++mt) {
        const int m = mt * 16 + r;
        short8 afrag[4];
#pragma unroll
        for (int kt = 0; kt < 4; ++kt)
            afrag[kt] = *(const short8*)&A_sh[m * LDA + kt * 32 + q * 8];
#pragma unroll
        for (int nt = 0; nt < 2; ++nt)
#pragma unroll
            for (int kt = 0; kt < 4; ++kt)
                acc[mt][nt] = __builtin_amdgcn_mfma_f32_16x16x32_bf16(
                    afrag[kt], bfrag[nt][kt], acc[mt][nt], 0, 0, 0);
    }

#pragma unroll
    for (int mt = 0; mt < 4; ++mt)
#pragma unroll
        for (int nt = 0; nt < 2; ++nt) {
            const int col = wave * 32 + nt * 16 + r;
#pragma unroll
            for (int reg = 0; reg < 4; ++reg) {
                const int row = mt * 16 + q * 4 + reg;
                C_sh[row * LDC + col] = acc[mt][nt][reg] + bias[nt];
            }
        }
    __syncthreads();

    {
        const int t = tid >> 7;
        const int j = tid & 127;
        const float* base = &C_sh[(t * TT) * LDC + j];
        float v[TT];
#pragma unroll
        for (int n = 0; n < TT; ++n) v[n] = base[n * LDC];
        float m = -1e30f;
#pragma unroll
        for (int n = TT - 1; n >= 1; --n) {
            m = fmaxf(m, v[n]);
            v[(n - 1) >> 1] += v[n];
        }
        m = fmaxf(m, v[0]);
        tree_vec[(long)(tree0 + t) * CC + j] = m;
    }
}

// ---------------- K2 (MFMA, hi/lo split): gx[dir][m=b*S+s][300] = X @ W_ih^T + b_ih
#define K2_NPAD 320
__global__ __launch_bounds__(256) void k2_mfma(const float* __restrict__ tree_vec,
                                               const float* __restrict__ w_ih_f,
                                               const float* __restrict__ b_ih_f,
                                               const float* __restrict__ w_ih_b,
                                               const float* __restrict__ b_ih_b,
                                               float* __restrict__ gx) {
    __shared__ __align__(16) unsigned short Ahi[32 * LDA];
    __shared__ __align__(16) unsigned short Alo[32 * LDA];
    __shared__ __align__(16) unsigned short Bhi[64 * LDA];
    __shared__ __align__(16) unsigned short Blo[64 * LDA];

    const int tid  = threadIdx.x;
    const int wave = tid >> 6;
    const int lane = tid & 63;
    const int r = lane & 15;
    const int q = lane >> 4;

    const int nb = blockIdx.x % 10;
    const int mb = blockIdx.x / 10;
    const int m0 = mb * 32;
    const int n0 = nb * 64;

#pragma unroll
    for (int i = 0; i < 4; ++i) {
        const int idx = tid + i * 256;
        const int row = idx >> 5;
        const int p   = idx & 31;
        const float4 v = ((const float4*)(tree_vec + (long)(m0 + row) * CC))[p];
        unsigned short* dh = &Ahi[row * LDA + p * 4];
        unsigned short* dl = &Alo[row * LDA + p * 4];
        float e[4] = {v.x, v.y, v.z, v.w};
#pragma unroll
        for (int c = 0; c < 4; ++c) {
            unsigned short h = f2bf_rne(e[c]);
            dh[c] = h;
            dl[c] = f2bf_rne(e[c] - bf2f(h));
        }
    }
#pragma unroll
    for (int i = 0; i < 8; ++i) {
        const int idx = tid + i * 256;
        const int row = idx >> 5;
        const int p   = idx & 31;
        const int n   = n0 + row;
        const int dir = (n >= K2_NPAD) ? 1 : 0;
        const int j   = n - dir * K2_NPAD;
        const int jj  = (j < G3) ? j : 0;
        const float* w = dir ? w_ih_b : w_ih_f;
        const float4 v = ((const float4*)(w + (long)jj * EE))[p];
        unsigned short* dh = &Bhi[row * LDA + p * 4];
        unsigned short* dl = &Blo[row * LDA + p * 4];
        float e[4] = {v.x, v.y, v.z, v.w};
#pragma unroll
        for (int c = 0; c < 4; ++c) {
            unsigned short h = f2bf_rne(e[c]);
            dh[c] = h;
            dl[c] = f2bf_rne(e[c] - bf2f(h));
        }
    }
    __syncthreads();

    const int nloc = wave * 16 + r;
    short8 bh[4], bl[4];
#pragma unroll
    for (int kt = 0; kt < 4; ++kt) {
        bh[kt] = *(const short8*)&Bhi[nloc * LDA + kt * 32 + q * 8];
        bl[kt] = *(const short8*)&Blo[nloc * LDA + kt * 32 + q * 8];
    }

    f32x4 acc[2];
    acc[0] = (f32x4)(0.f); acc[1] = (f32x4)(0.f);
#pragma unroll
    for (int mt = 0; mt < 2; ++mt) {
        const int m = mt * 16 + r;
#pragma unroll
        for (int kt = 0; kt < 4; ++kt) {
            short8 ah = *(const short8*)&Ahi[m * LDA + kt * 32 + q * 8];
            short8 al = *(const short8*)&Alo[m * LDA + kt * 32 + q * 8];
            acc[mt] = __builtin_amdgcn_mfma_f32_16x16x32_bf16(ah, bh[kt], acc[mt], 0, 0, 0);
            acc[mt] = __builtin_amdgcn_mfma_f32_16x16x32_bf16(ah, bl[kt], acc[mt], 0, 0, 0);
            acc[mt] = __builtin_amdgcn_mfma_f32_16x16x32_bf16(al, bh[kt], acc[mt], 0, 0, 0);
        }
    }

    const int ng  = n0 + wave * 16 + r;
    const int dir = (ng >= K2_NPAD) ? 1 : 0;
    const int j   = ng - dir * K2_NPAD;
    const bool valid = (j < G3);
    const float bias = valid ? (dir ? b_ih_b[j] : b_ih_f[j]) : 0.f;
    float* gxd = gx + (long)dir * NTREE * G3;
    if (valid) {
#pragma unroll
        for (int mt = 0; mt < 2; ++mt)
#pragma unroll
            for (int reg = 0; reg < 4; ++reg) {
                const int m = m0 + mt * 16 + q * 4 + reg;
                gxd[(long)m * G3 + j] = acc[mt][reg] + bias;
            }
    }
}

// ---------------- K3 v5: 1 chain/block (128 blocks, 4 waves), fp16 MFMA matvec,
// row-permuted W_hh so each wave owns channels [25w,25w+25) completely:
// gates redistribute WAVE-LOCALLY (no barrier); only the h broadcast needs a
// barrier -> ONE lgkm-only barrier per step, h double-buffered (race-free at
// skew<1 step).
__global__ __launch_bounds__(256, 1) void k3_gru(const float* __restrict__ gx,
                                                 const float* __restrict__ w_hh_f,
                                                 const float* __restrict__ b_hh_f,
                                                 const float* __restrict__ w_hh_b,
                                                 const float* __restrict__ b_hh_b,
                                                 float* __restrict__ pool) {
    const int bid = blockIdx.x;   // 0..127
    const int dir = bid & 1;
    const int b = bid >> 1;
    const float* w_hh = dir ? w_hh_b : w_hh_f;
    const float* b_hh = dir ? b_hh_b : b_hh_f;

    __shared__ __align__(16) _Float16 h_sh[2][128];   // double-buffered h (fp16, k-pad 0)
    __shared__ float g_sh[4][80];                     // per-wave gate slab (permuted rows)

    const int tid  = threadIdx.x;
    const int wave = tid >> 6;
    const int lane = tid & 63;
    const int r = lane & 15;
    const int q = lane >> 4;

    // ---- persistent B fragments (fp16), PERMUTED rows: wave w owns channels
    // [25w, 25w+25). Local row l = 16*i + r; l<25 -> gate r(ch=l), l<50 -> gate z,
    // l<75 -> gate n, l>=75 -> zero pad. Global W_hh row = gate*100 + 25w + ch.
    f16x8 bf[5][4];
#pragma unroll
    for (int i = 0; i < 5; ++i) {
        const int l = i * 16 + r;
        const int gate = l / 25;
        const int ch   = l - gate * 25;
        const bool nv  = (l < 75);
        const int row  = gate * HH + wave * 25 + ch;
#pragma unroll
        for (int kt = 0; kt < 4; ++kt) {
            f16x8 f;
#pragma unroll
            for (int e = 0; e < 8; ++e) {
                const int k = kt * 32 + q * 8 + e;
                f[e] = (_Float16)((nv && k < HH) ? w_hh[row * HH + k] : 0.f);
            }
            bf[i][kt] = f;
        }
    }

    // activation lane: lane m<25 of wave w owns channel c = 25w + m
    const int m = lane;
    const int c = wave * 25 + m;
    const bool act = (m < 25);
    float br = 0.f, bz = 0.f, bn = 0.f;
    if (act) { br = b_hh[c]; bz = b_hh[HH + c]; bn = b_hh[2 * HH + c]; }

    if (tid < 128) { h_sh[0][tid] = (_Float16)0.f; h_sh[1][tid] = (_Float16)0.f; }

    const float* gxd = gx + (long)dir * NTREE * G3;
    const int sstep = dir ? -1 : 1;
    int s = dir ? (SS - 1) : 0;
    float xr = 0.f, xz = 0.f, xn = 0.f;
    if (act) {
        const float* row0 = gxd + ((long)b * SS + s) * G3;
        xr = row0[c]; xz = row0[HH + c]; xn = row0[2 * HH + c];
    }
    float hj = 0.f, hmax = -1e30f;
    __syncthreads();

    for (int t = 0; t < SS; ++t) {
        const int p = t & 1;
        // ---- prefetch next step's gx (survives the lgkm-only barrier; waited at use)
        const int s_n = s + sstep;
        float xrn = 0.f, xzn = 0.f, xnn = 0.f;
        if (act && t < SS - 1) {
            const float* row0 = gxd + ((long)b * SS + s_n) * G3;
            xrn = row0[c]; xzn = row0[HH + c]; xnn = row0[2 * HH + c];
        }

        // ---- matvec: A = h (broadcast to all 16 rows), B = permuted W_hh frags
        f16x8 a[4];
#pragma unroll
        for (int kt = 0; kt < 4; ++kt)
            a[kt] = *(const f16x8*)&h_sh[p][kt * 32 + q * 8];   // broadcast b128
        f32x4 acc[5];
#pragma unroll
        for (int i = 0; i < 5; ++i) {
            acc[i] = (f32x4)(0.f);
#pragma unroll
            for (int kt = 0; kt < 4; ++kt)
                acc[i] = __builtin_amdgcn_mfma_f32_16x16x32_f16(a[kt], bf[i][kt], acc[i], 0, 0, 0);
        }
        // C row 0 = lanes 0..15, reg 0 -> wave-local gate slab (consecutive floats)
        if (q == 0) {
#pragma unroll
            for (int i = 0; i < 5; ++i)
                g_sh[wave][i * 16 + r] = acc[i][0];
        }
        // wave-local read-after-write: lgkm waits only, no barrier
        if (act) {
            const float ghr = g_sh[wave][m];
            const float ghz = g_sh[wave][25 + m];
            const float ghn = g_sh[wave][50 + m];
            const float rg = fast_sigmoid(xr + ghr + br);
            const float zg = fast_sigmoid(xz + ghz + bz);
            const float ng = fast_tanh(xn + rg * (ghn + bn));
            hj = (1.f - zg) * ng + zg * hj;
            hmax = fmaxf(hmax, hj);
            h_sh[1 - p][c] = (_Float16)hj;   // next step's buffer
            xr = xrn; xz = xzn; xn = xnn;
        }
        BAR();   // single barrier per step: publish h to all waves
        s = s_n;
    }
    if (act) pool[(long)b * (2 * HH) + dir * HH + c] = hmax;
}

// ---------------- K4: out[b][o] = fc_b[o] + pool[b,:] . fc_w[o,:]
__global__ __launch_bounds__(256) void k4_fc(const float* __restrict__ pool,
                                             const float* __restrict__ fc_w,
                                             const float* __restrict__ fc_b,
                                             float* __restrict__ out) {
    const int b = blockIdx.x;
    __shared__ __align__(16) float p_sh[2 * HH];
    const int t = threadIdx.x;
    if (t < 2 * HH) p_sh[t] = pool[(long)b * (2 * HH) + t];
    __syncthreads();
    if (t < OUTD) {
        const float4* wr4 = (const float4*)(fc_w + (long)t * (2 * HH));
        const float4* p4 = (const float4*)p_sh;
        float a0 = 0.f, a1 = 0.f;
#pragma unroll
        for (int k = 0; k < 50; k += 2) {
            float4 w0 = wr4[k],   p0 = p4[k];
            float4 w1 = wr4[k+1], p1 = p4[k+1];
            a0 += w0.x*p0.x + w0.y*p0.y + w0.z*p0.z + w0.w*p0.w;
            a1 += w1.x*p1.x + w1.y*p1.y + w1.z*p1.z + w1.w*p1.w;
        }
        out[(long)b * OUTD + t] = fc_b[t] + a0 + a1;
    }
}

extern "C" void kernel_launch(void* const* d_in, const int* in_sizes, int n_in,
                              void* d_out, int out_size, void* d_ws, size_t ws_size,
                              hipStream_t stream) {
    const int*   tok    = (const int*)d_in[0];
    const float* emb    = (const float*)d_in[4];
    const float* w_lin  = (const float*)d_in[5];
    const float* b_lin  = (const float*)d_in[6];
    const float* w_ih_f = (const float*)d_in[7];
    const float* w_hh_f = (const float*)d_in[8];
    const float* b_ih_f = (const float*)d_in[9];
    const float* b_hh_f = (const float*)d_in[10];
    const float* w_ih_b = (const float*)d_in[11];
    const float* w_hh_b = (const float*)d_in[12];
    const float* b_ih_b = (const float*)d_in[13];
    const float* b_hh_b = (const float*)d_in[14];
    const float* fc_w   = (const float*)d_in[15];
    const float* fc_b   = (const float*)d_in[16];

    float* ws       = (float*)d_ws;
    float* tree_vec = ws;                                   // 12800*128
    float* gx       = tree_vec + (long)NTREE * CC;          // 2*12800*300
    float* pool     = gx + (long)2 * NTREE * G3;            // 64*200
    float* out      = (float*)d_out;

    k1_mfma<<<NTREE / K1_TPI, 256, 0, stream>>>(tok, emb, w_lin, b_lin, tree_vec);
    k2_mfma<<<(NTREE / 32) * 10, 256, 0, stream>>>(tree_vec, w_ih_f, b_ih_f, w_ih_b, b_ih_b, gx);
    k3_gru <<<2 * BB, 256, 0, stream>>>(gx, w_hh_f, b_hh_f, w_hh_b, b_hh_b, pool);
    k4_fc  <<<BB, 256, 0, stream>>>(pool, fc_w, fc_b, out);
}

// Round 8
// 245.671 us; speedup vs baseline: 1.9548x; 1.1253x over previous
//
#include <hip/hip_runtime.h>
#include <hip/hip_bf16.h>
#include <math.h>

// Problem dims (fixed by reference)
#define BB 64
#define SS 200
#define TT 32
#define EE 128
#define CC 128
#define HH 100
#define G3 300           // 3*H
#define OUTD 104
#define NTREE (BB*SS)    // 12800

typedef __attribute__((ext_vector_type(4))) float f32x4;
typedef _Float16 f16x8 __attribute__((ext_vector_type(8)));

__device__ inline float fast_sigmoid(float x) {
    return __builtin_amdgcn_rcpf(1.f + __builtin_amdgcn_exp2f(-1.4426950408889634f * x));
}
__device__ inline float fast_tanh(float x) {
    return 1.f - 2.f * __builtin_amdgcn_rcpf(1.f + __builtin_amdgcn_exp2f(2.8853900817779268f * x));
}

// LDS-only barrier: waits ds-ops (lgkmcnt) but does NOT drain vmcnt, so in-flight
// global prefetch loads stay outstanding across the barrier (waited at use).
#define BAR() asm volatile("s_waitcnt lgkmcnt(0)\n\ts_barrier" ::: "memory")

// Workspace byte offsets (total 34.2 MB, fits the >=37.3 MB ws proven in round 1)
//   wl   @ 0        : 32768 B   (k1 W_lin fragment image, fp16)
//   k2b  @ 32768    : 163840 B  (k2 W_ih fragment image, fp16)
//   thi  @ 196608   : 3276800 B (tree_vec, fp16)
//   gx   @ 3473408  : 30720000 B (fp32)
//   pool @ 0        : 51200 B   -- aliases wl/k2b; k3 writes it AFTER k2 read them.

// ---------------- K0: build weight-fragment images (runs every launch; idempotent)
__global__ __launch_bounds__(256) void k0_prep(const float* __restrict__ w_lin,
                                               const float* __restrict__ w_ih_f,
                                               const float* __restrict__ w_ih_b,
                                               _Float16* __restrict__ wl,
                                               _Float16* __restrict__ k2b) {
    const int tid  = threadIdx.x;
    const int wave = tid >> 6;
    const int lane = tid & 63;
    const int r = lane & 15;
    const int q = lane >> 4;
    if (blockIdx.x == 0) {
        // k1 image: wave w, lane(r,q), nt, kt -> W_lin[n=w*32+nt*16+r][k=kt*32+q*8 ..+8]
#pragma unroll
        for (int nt = 0; nt < 2; ++nt)
#pragma unroll
            for (int kt = 0; kt < 4; ++kt) {
                const int n = wave * 32 + nt * 16 + r;
                const float* src = w_lin + (long)n * EE + kt * 32 + q * 8;
                f16x8 f;
#pragma unroll
                for (int e = 0; e < 8; ++e) f[e] = (_Float16)src[e];
                *(f16x8*)&wl[(size_t)((((wave * 2 + nt) * 4 + kt) * 64) + lane) * 8] = f;
            }
    } else {
        // k2 image: nb, wave w, lane(r,q), kt -> W_ih[padded n = nb*64+w*16+r][k=kt*32+q*8]
        const int nb = blockIdx.x - 1;           // 0..9
        const int n = nb * 64 + wave * 16 + r;
        const int dir = (n >= 320) ? 1 : 0;
        const int j = n - dir * 320;
        const int jj = (j < G3) ? j : 0;         // pad rows clamped (results discarded)
        const float* w = dir ? w_ih_b : w_ih_f;
#pragma unroll
        for (int kt = 0; kt < 4; ++kt) {
            const float* src = w + (long)jj * EE + kt * 32 + q * 8;
            f16x8 f;
#pragma unroll
            for (int e = 0; e < 8; ++e) f[e] = (_Float16)src[e];
            *(f16x8*)&k2b[(size_t)((((nb * 4 + wave) * 4 + kt) * 64) + lane) * 8] = f;
        }
    }
}

// ---------------- K1 (fp16 MFMA): embed-gather -> GEMM vs W_lin^T -> bias -> tree-sum -> maxpool
#define K1_TPI 2
#define AROWS (K1_TPI*TT)        // 64
#define LDA 136                  // fp16/row: 128 + 8 pad
#define LDC 132                  // fp32/row: 128 + 4 pad

__global__ __launch_bounds__(256) void k1_mfma(const int* __restrict__ tok,
                                               const float* __restrict__ emb,
                                               const _Float16* __restrict__ wl,
                                               const float* __restrict__ b_lin,
                                               _Float16* __restrict__ thi) {
    __shared__ __align__(16) _Float16 A_sh[AROWS * LDA];   // 17408 B
    __shared__ __align__(16) float C_sh[AROWS * LDC];      // 33792 B
    __shared__ int tok_sh[AROWS];

    const int tid  = threadIdx.x;
    const int wave = tid >> 6;
    const int lane = tid & 63;
    const int r = lane & 15;
    const int q = lane >> 4;

    // ---- B fragments: 8 coalesced 16B loads from the prebuilt image (no cvt VALU)
    f16x8 bfrag[2][4];
    float bias[2];
#pragma unroll
    for (int nt = 0; nt < 2; ++nt) {
        bias[nt] = b_lin[wave * 32 + nt * 16 + r];
#pragma unroll
        for (int kt = 0; kt < 4; ++kt)
            bfrag[nt][kt] = *(const f16x8*)&wl[(size_t)((((wave * 2 + nt) * 4 + kt) * 64) + lane) * 8];
    }

    const int tree0 = blockIdx.x * K1_TPI;
    if (tid < AROWS) tok_sh[tid] = tok[tree0 * TT + tid];
    __syncthreads();

    // ---- gather embeddings -> fp16 LDS (single cvt per element)
#pragma unroll
    for (int i = 0; i < 8; ++i) {
        const int idx = tid + i * 256;
        const int row = idx >> 5;
        const int p   = idx & 31;
        const float4 e = ((const float4*)(emb + (long)tok_sh[row] * EE))[p];
        _Float16* dst = &A_sh[row * LDA + p * 4];
        dst[0] = (_Float16)e.x; dst[1] = (_Float16)e.y;
        dst[2] = (_Float16)e.z; dst[3] = (_Float16)e.w;
    }
    __syncthreads();

    f32x4 acc[4][2];
#pragma unroll
    for (int mt = 0; mt < 4; ++mt)
#pragma unroll
        for (int nt = 0; nt < 2; ++nt) acc[mt][nt] = (f32x4)(0.f);

#pragma unroll
    for (int mt = 0; mt < 4; ++mt) {
        const int m = mt * 16 + r;
        f16x8 afrag[4];
#pragma unroll
        for (int kt = 0; kt < 4; ++kt)
            afrag[kt] = *(const f16x8*)&A_sh[m * LDA + kt * 32 + q * 8];
#pragma unroll
        for (int nt = 0; nt < 2; ++nt)
#pragma unroll
            for (int kt = 0; kt < 4; ++kt)
                acc[mt][nt] = __builtin_amdgcn_mfma_f32_16x16x32_f16(
                    afrag[kt], bfrag[nt][kt], acc[mt][nt], 0, 0, 0);
    }

#pragma unroll
    for (int mt = 0; mt < 4; ++mt)
#pragma unroll
        for (int nt = 0; nt < 2; ++nt) {
            const int col = wave * 32 + nt * 16 + r;
#pragma unroll
            for (int reg = 0; reg < 4; ++reg) {
                const int row = mt * 16 + q * 4 + reg;
                C_sh[row * LDC + col] = acc[mt][nt][reg] + bias[nt];
            }
        }
    __syncthreads();

    // ---- tree-sum + maxpool in registers (descending index = topological order)
    {
        const int t = tid >> 7;
        const int j = tid & 127;
        const float* base = &C_sh[(t * TT) * LDC + j];
        float v[TT];
#pragma unroll
        for (int n = 0; n < TT; ++n) v[n] = base[n * LDC];
        float mx = -1e30f;
#pragma unroll
        for (int n = TT - 1; n >= 1; --n) {
            mx = fmaxf(mx, v[n]);
            v[(n - 1) >> 1] += v[n];
        }
        mx = fmaxf(mx, v[0]);
        thi[(size_t)(tree0 + t) * CC + j] = (_Float16)mx;   // fp32 sums, one fp16 round
    }
}

// ---------------- K2 (fp16 MFMA): gx[dir][m=b*S+s][300] = X @ W_ih^T + b_ih
// B fragments come prebuilt (registers, coalesced); A is a copy-only fp16 stage.
__global__ __launch_bounds__(256) void k2_mfma(const _Float16* __restrict__ thi,
                                               const _Float16* __restrict__ k2b,
                                               const float* __restrict__ b_ih_f,
                                               const float* __restrict__ b_ih_b,
                                               float* __restrict__ gx) {
    __shared__ __align__(16) _Float16 Ah[32 * LDA];   // 8704 B

    const int tid  = threadIdx.x;
    const int wave = tid >> 6;
    const int lane = tid & 63;
    const int r = lane & 15;
    const int q = lane >> 4;

    const int nb = blockIdx.x % 10;
    const int mb = blockIdx.x / 10;
    const int m0 = mb * 32;
    const int n0 = nb * 64;

    // stage A: 32 rows x 128 fp16 = 512 f16x8; 2 per thread (copy, no conversion)
#pragma unroll
    for (int i = 0; i < 2; ++i) {
        const int idx = tid + i * 256;
        const int row = idx >> 4;
        const int p   = idx & 15;
        f16x8 v = *(const f16x8*)&thi[(size_t)(m0 + row) * CC + p * 8];
        *(f16x8*)&Ah[row * LDA + p * 8] = v;
    }
    // B fragments: 4 coalesced 16B loads
    f16x8 bh[4];
#pragma unroll
    for (int kt = 0; kt < 4; ++kt)
        bh[kt] = *(const f16x8*)&k2b[(size_t)((((nb * 4 + wave) * 4 + kt) * 64) + lane) * 8];
    __syncthreads();

    f32x4 acc[2];
    acc[0] = (f32x4)(0.f); acc[1] = (f32x4)(0.f);
#pragma unroll
    for (int mt = 0; mt < 2; ++mt) {
        const int m = mt * 16 + r;
#pragma unroll
        for (int kt = 0; kt < 4; ++kt) {
            f16x8 a = *(const f16x8*)&Ah[m * LDA + kt * 32 + q * 8];
            acc[mt] = __builtin_amdgcn_mfma_f32_16x16x32_f16(a, bh[kt], acc[mt], 0, 0, 0);
        }
    }

    const int ng  = n0 + wave * 16 + r;
    const int dir = (ng >= 320) ? 1 : 0;
    const int j   = ng - dir * 320;
    const bool valid = (j < G3);
    const float bias = valid ? (dir ? b_ih_b[j] : b_ih_f[j]) : 0.f;
    float* gxd = gx + (long)dir * NTREE * G3;
    if (valid) {
#pragma unroll
        for (int mt = 0; mt < 2; ++mt)
#pragma unroll
            for (int reg = 0; reg < 4; ++reg) {
                const int m = m0 + mt * 16 + q * 4 + reg;
                gxd[(long)m * G3 + j] = acc[mt][reg] + bias;
            }
    }
}

// ---------------- K3 v5 (unchanged, measured 104 us): 1 chain/block, fp16 MFMA matvec,
// row-permuted W_hh (wave-local gates), one lgkm-only barrier/step, h double-buffered.
__global__ __launch_bounds__(256, 1) void k3_gru(const float* __restrict__ gx,
                                                 const float* __restrict__ w_hh_f,
                                                 const float* __restrict__ b_hh_f,
                                                 const float* __restrict__ w_hh_b,
                                                 const float* __restrict__ b_hh_b,
                                                 float* __restrict__ pool) {
    const int bid = blockIdx.x;   // 0..127
    const int dir = bid & 1;
    const int b = bid >> 1;
    const float* w_hh = dir ? w_hh_b : w_hh_f;
    const float* b_hh = dir ? b_hh_b : b_hh_f;

    __shared__ __align__(16) _Float16 h_sh[2][128];
    __shared__ float g_sh[4][80];

    const int tid  = threadIdx.x;
    const int wave = tid >> 6;
    const int lane = tid & 63;
    const int r = lane & 15;
    const int q = lane >> 4;

    f16x8 bf[5][4];
#pragma unroll
    for (int i = 0; i < 5; ++i) {
        const int l = i * 16 + r;
        const int gate = l / 25;
        const int ch   = l - gate * 25;
        const bool nv  = (l < 75);
        const int row  = gate * HH + wave * 25 + ch;
#pragma unroll
        for (int kt = 0; kt < 4; ++kt) {
            f16x8 f;
#pragma unroll
            for (int e = 0; e < 8; ++e) {
                const int k = kt * 32 + q * 8 + e;
                f[e] = (_Float16)((nv && k < HH) ? w_hh[row * HH + k] : 0.f);
            }
            bf[i][kt] = f;
        }
    }

    const int m = lane;
    const int c = wave * 25 + m;
    const bool act = (m < 25);
    float br = 0.f, bz = 0.f, bn = 0.f;
    if (act) { br = b_hh[c]; bz = b_hh[HH + c]; bn = b_hh[2 * HH + c]; }

    if (tid < 128) { h_sh[0][tid] = (_Float16)0.f; h_sh[1][tid] = (_Float16)0.f; }

    const float* gxd = gx + (long)dir * NTREE * G3;
    const int sstep = dir ? -1 : 1;
    int s = dir ? (SS - 1) : 0;
    float xr = 0.f, xz = 0.f, xn = 0.f;
    if (act) {
        const float* row0 = gxd + ((long)b * SS + s) * G3;
        xr = row0[c]; xz = row0[HH + c]; xn = row0[2 * HH + c];
    }
    float hj = 0.f, hmax = -1e30f;
    __syncthreads();

    for (int t = 0; t < SS; ++t) {
        const int p = t & 1;
        const int s_n = s + sstep;
        float xrn = 0.f, xzn = 0.f, xnn = 0.f;
        if (act && t < SS - 1) {
            const float* row0 = gxd + ((long)b * SS + s_n) * G3;
            xrn = row0[c]; xzn = row0[HH + c]; xnn = row0[2 * HH + c];
        }

        f16x8 a[4];
#pragma unroll
        for (int kt = 0; kt < 4; ++kt)
            a[kt] = *(const f16x8*)&h_sh[p][kt * 32 + q * 8];
        f32x4 acc[5];
#pragma unroll
        for (int i = 0; i < 5; ++i) {
            acc[i] = (f32x4)(0.f);
#pragma unroll
            for (int kt = 0; kt < 4; ++kt)
                acc[i] = __builtin_amdgcn_mfma_f32_16x16x32_f16(a[kt], bf[i][kt], acc[i], 0, 0, 0);
        }
        if (q == 0) {
#pragma unroll
            for (int i = 0; i < 5; ++i)
                g_sh[wave][i * 16 + r] = acc[i][0];
        }
        if (act) {
            const float ghr = g_sh[wave][m];
            const float ghz = g_sh[wave][25 + m];
            const float ghn = g_sh[wave][50 + m];
            const float rg = fast_sigmoid(xr + ghr + br);
            const float zg = fast_sigmoid(xz + ghz + bz);
            const float ng = fast_tanh(xn + rg * (ghn + bn));
            hj = (1.f - zg) * ng + zg * hj;
            hmax = fmaxf(hmax, hj);
            h_sh[1 - p][c] = (_Float16)hj;
            xr = xrn; xz = xzn; xn = xnn;
        }
        BAR();
        s = s_n;
    }
    if (act) pool[(long)b * (2 * HH) + dir * HH + c] = hmax;
}

// ---------------- K4: out[b][o] = fc_b[o] + pool[b,:] . fc_w[o,:]
__global__ __launch_bounds__(256) void k4_fc(const float* __restrict__ pool,
                                             const float* __restrict__ fc_w,
                                             const float* __restrict__ fc_b,
                                             float* __restrict__ out) {
    const int b = blockIdx.x;
    __shared__ __align__(16) float p_sh[2 * HH];
    const int t = threadIdx.x;
    if (t < 2 * HH) p_sh[t] = pool[(long)b * (2 * HH) + t];
    __syncthreads();
    if (t < OUTD) {
        const float4* wr4 = (const float4*)(fc_w + (long)t * (2 * HH));
        const float4* p4 = (const float4*)p_sh;
        float a0 = 0.f, a1 = 0.f;
#pragma unroll
        for (int k = 0; k < 50; k += 2) {
            float4 w0 = wr4[k],   p0 = p4[k];
            float4 w1 = wr4[k+1], p1 = p4[k+1];
            a0 += w0.x*p0.x + w0.y*p0.y + w0.z*p0.z + w0.w*p0.w;
            a1 += w1.x*p1.x + w1.y*p1.y + w1.z*p1.z + w1.w*p1.w;
        }
        out[(long)b * OUTD + t] = fc_b[t] + a0 + a1;
    }
}

extern "C" void kernel_launch(void* const* d_in, const int* in_sizes, int n_in,
                              void* d_out, int out_size, void* d_ws, size_t ws_size,
                              hipStream_t stream) {
    const int*   tok    = (const int*)d_in[0];
    const float* emb    = (const float*)d_in[4];
    const float* w_lin  = (const float*)d_in[5];
    const float* b_lin  = (const float*)d_in[6];
    const float* w_ih_f = (const float*)d_in[7];
    const float* w_hh_f = (const float*)d_in[8];
    const float* b_ih_f = (const float*)d_in[9];
    const float* b_hh_f = (const float*)d_in[10];
    const float* w_ih_b = (const float*)d_in[11];
    const float* w_hh_b = (const float*)d_in[12];
    const float* b_ih_b = (const float*)d_in[13];
    const float* b_hh_b = (const float*)d_in[14];
    const float* fc_w   = (const float*)d_in[15];
    const float* fc_b   = (const float*)d_in[16];

    char* wsb = (char*)d_ws;
    _Float16* wl   = (_Float16*)(wsb);             // 32768 B
    _Float16* k2b  = (_Float16*)(wsb + 32768);     // 163840 B
    _Float16* thi  = (_Float16*)(wsb + 196608);    // 3276800 B
    float*    gx   = (float*)(wsb + 3473408);      // 30720000 B
    float*    pool = (float*)(wsb);                // aliases wl/k2b: k3 runs after k2
    float*    out  = (float*)d_out;

    k0_prep<<<11, 256, 0, stream>>>(w_lin, w_ih_f, w_ih_b, wl, k2b);
    k1_mfma<<<NTREE / K1_TPI, 256, 0, stream>>>(tok, emb, wl, b_lin, thi);
    k2_mfma<<<(NTREE / 32) * 10, 256, 0, stream>>>(thi, k2b, b_ih_f, b_ih_b, gx);
    k3_gru <<<2 * BB, 256, 0, stream>>>(gx, w_hh_f, b_hh_f, w_hh_b, b_hh_b, pool);
    k4_fc  <<<BB, 256, 0, stream>>>(pool, fc_w, fc_b, out);
}